// Round 20
// baseline (625.502 us; speedup 1.0000x reference)
//
#include <hip/hip_runtime.h>
#include <stdint.h>

#define N 8192
#define D 512
#define NEG -1e30f

typedef _Float16 f16;
typedef f16 f16x4 __attribute__((ext_vector_type(4)));
typedef f16 f16x8 __attribute__((ext_vector_type(8)));
typedef float f32x4v __attribute__((ext_vector_type(4)));
typedef float f32x16 __attribute__((ext_vector_type(16)));
typedef unsigned long long u64;

// ---- workspace layout (bytes) ----
#define XH_OFF   0ull
#define WQH_OFF  (XH_OFF + 8192ull * 512 * 2)
#define WKH_OFF  (WQH_OFF + 512ull * 512 * 2)
#define WVH_OFF  (WKH_OFF + 512ull * 512 * 2)
#define QH_OFF   (WVH_OFF + 512ull * 512 * 2)
#define KH_OFF   (QH_OFF + 8192ull * 512 * 2)
#define VT_OFF   (KH_OFF + 8192ull * 512 * 2)
#define PART_SZ  (8192ull * 512 * 2)                // one fp16 partial, 8 MB
#define P1_OFF   (VT_OFF + 8192ull * 512 * 2)
#define ML_OFF   (P1_OFF + PART_SZ)                 // float2[2][N]
#define ADJ_OFF  (ML_OFF + 2ull * N * 8)            // u64 bitmap, 8 MB

// ---------------- fp32 -> fp16 conversion ----------------
__global__ __launch_bounds__(256) void cvt_fp16(
    const float* __restrict__ X,
    const float* __restrict__ Wq, const float* __restrict__ Wk, const float* __restrict__ Wv,
    f16* __restrict__ Xh,
    f16* __restrict__ Wqh, f16* __restrict__ Wkh, f16* __restrict__ Wvh)
{
    const int idx = blockIdx.x * 256 + threadIdx.x;
    const float* src; f16* dst; int off;
    if (idx < 1048576)      { src = X;  dst = Xh;  off = idx; }
    else if (idx < 1114112) { src = Wq; dst = Wqh; off = idx - 1048576; }
    else if (idx < 1179648) { src = Wk; dst = Wkh; off = idx - 1114112; }
    else                    { src = Wv; dst = Wvh; off = idx - 1179648; }
    const float4 v = ((const float4*)src)[off];
    f16x4 h; h.x = (f16)v.x; h.y = (f16)v.y; h.z = (f16)v.z; h.w = (f16)v.w;
    *(f16x4*)(dst + (size_t)off * 4) = h;
}

// ---------------- QKV via MFMA (unchanged) ----------------
__global__ __launch_bounds__(256) void qkv_mfma(
    const f16* __restrict__ Xh,
    const f16* __restrict__ Wqh, const f16* __restrict__ Wkh, const f16* __restrict__ Wvh,
    f16* __restrict__ qh, f16* __restrict__ kh, f16* __restrict__ vt)
{
    const int t    = threadIdx.x;
    const int w    = t >> 6;
    const int lane = t & 63;
    const int lo   = lane & 31;
    const int hi   = lane >> 5;
    const int z    = blockIdx.z;

    int m0, c0; const f16 *Ap, *Bp; f16* Yp; size_t ldy;
    if (z == 2) {
        m0 = blockIdx.x * 128 + w * 32; c0 = blockIdx.y * 128;
        Ap = Wvh; Bp = Xh; Yp = vt; ldy = N;
    } else {
        m0 = blockIdx.y * 128 + w * 32; c0 = blockIdx.x * 128;
        Ap = Xh; Bp = z ? Wkh : Wqh; Yp = z ? kh : qh; ldy = D;
    }

    const f16* arow = Ap + (size_t)(m0 + lo) * D + hi * 8;
    const f16* brow[4];
#pragma unroll
    for (int nn = 0; nn < 4; ++nn)
        brow[nn] = Bp + (size_t)(c0 + nn * 32 + lo) * D + hi * 8;

    f32x16 acc[4];
#pragma unroll
    for (int nn = 0; nn < 4; ++nn)
#pragma unroll
        for (int e = 0; e < 16; ++e) acc[nn][e] = 0.f;

#pragma unroll 4
    for (int ks = 0; ks < 32; ++ks) {
        const f16x8 a = *(const f16x8*)(arow + ks * 16);
#pragma unroll
        for (int nn = 0; nn < 4; ++nn) {
            const f16x8 b = *(const f16x8*)(brow[nn] + ks * 16);
            acc[nn] = __builtin_amdgcn_mfma_f32_32x32x16_f16(a, b, acc[nn], 0, 0, 0);
        }
    }

#pragma unroll
    for (int nn = 0; nn < 4; ++nn)
#pragma unroll
        for (int r = 0; r < 16; ++r) {
            const int row = m0 + (r & 3) + 8 * (r >> 2) + 4 * hi;
            Yp[(size_t)row * ldy + c0 + nn * 32 + lo] = (f16)acc[nn][r];
        }
}

// ---------------- adjacency bit-pack, COALESCED (r13) ----------------
// adjb[iw][j] bit b = adj[iw*64+b][j]
__global__ __launch_bounds__(256) void pack_adj(
    const int* __restrict__ adj, u64* __restrict__ adjb)
{
    const int idx = blockIdx.x * 256 + threadIdx.x;   // 1,048,576 total
    const int j   = idx & (N - 1);
    const int iw  = idx >> 13;                        // 0..127
    const int* src = adj + (size_t)iw * 64 * N + j;
    u64 bits = 0;
#pragma unroll 8
    for (int i2 = 0; i2 < 64; ++i2)
        bits |= (u64)(src[(size_t)i2 * N] != 0) << i2;
    adjb[(size_t)iw * N + j] = bits;
}

// ---------------- attention v10: champion phases, BJ=32 / BI=128 ----------------
// grid = 256 j-tiles x 2 i-halves = 512 blocks, 256 thr / 4 waves, 2 blocks/CU.
// Per tile (32j x 128i): QK^T waves split i-bands (w*32); PV waves split
// d-bands (w*128). Stats exchange + wave0 combine + scl broadcast identical to
// the 432-us champion. Q-LDS traffic/tile halves (32KB Q tile); O-acc = 64
// regs (well inside the 256 unified budget); rescale halves + defer-skip.
__global__ __launch_bounds__(256, 2) void attn_v10(
    const f16* __restrict__ qh, const f16* __restrict__ kh,
    const f16* __restrict__ vt, const u64* __restrict__ adjb,
    f16* __restrict__ part0, f16* __restrict__ part1, float2* __restrict__ ml)
{
    __shared__ char  Qs[32 * 1040];     // 33,280
    __shared__ char  Psb[32 * 272];     //  8,704  (row j, 128 i x 2B + pad)
    __shared__ float mlxm[4 * 32];
    __shared__ float mlxl[4 * 32];
    __shared__ float mrow[32];
    __shared__ float lrow[32];
    __shared__ float scl[32];

    const int t  = threadIdx.x;
    const int w  = t >> 6;
    const int l  = t & 63;
    const int cl = l & 15;     // mfma column lane
    const int hq = l >> 4;     // k-group / row-quad

    // XCD-aware mapping: i-half pinned per XCD quad, bijective j-tile
    const int b   = blockIdx.x;
    const int xcd = b & 7;
    const int ib  = xcd >> 2;                   // i-half 0/1
    const int jt_ = (xcd & 3) * 64 + (b >> 3);  // 0..255
    const int j0    = jt_ * 32;
    const int ibase = ib * 4096;

    f16* pb = (ib == 0) ? part0 : part1;

    // ---- stage Q[j0..j0+31][*] into Qs (row stride 1040) ----
    for (int c = t; c < 32 * 64; c += 256) {
        const int row = c >> 6, off = c & 63;
        f16x8 v = *(const f16x8*)(qh + (size_t)(j0 + row) * D + off * 8);
        *(f16x8*)(Qs + row * 1040 + off * 16) = v;
    }
    if (t < 32) { mrow[t] = NEG; lrow[t] = 0.f; }
    __syncthreads();

    f32x4v oacc[2][8];                          // [jt][dt], 64 regs
#pragma unroll
    for (int jt = 0; jt < 2; ++jt)
#pragma unroll
        for (int dt = 0; dt < 8; ++dt) {
            oacc[jt][dt][0] = 0.f; oacc[jt][dt][1] = 0.f;
            oacc[jt][dt][2] = 0.f; oacc[jt][dt][3] = 0.f;
        }

    const char* qbase0 = Qs + cl * 1040;
    const char* qbase1 = Qs + (16 + cl) * 1040;
    const int qoff = hq * 16;
    const int bsh  = (w & 1) * 32;              // i-bit base within the u64 word

    for (int it = 0; it < 32; ++it) {
        const int i0t   = ibase + it * 128;
        const int iband = i0t + w * 32;

        // ---- mask bitmap: 2 coalesced u64 loads per lane ----
        const u64* ab = adjb + ((size_t)(iband >> 6)) * N + j0 + cl;
        const u64 wd0 = ab[0];
        const u64 wd1 = ab[16];

        // ---- QK^T: wave w covers i-band w*32; sacc[jt][it2] ----
        f32x4v sacc[2][2];
#pragma unroll
        for (int jt = 0; jt < 2; ++jt)
#pragma unroll
            for (int it2 = 0; it2 < 2; ++it2) {
                sacc[jt][it2][0] = 0.f; sacc[jt][it2][1] = 0.f;
                sacc[jt][it2][2] = 0.f; sacc[jt][it2][3] = 0.f;
            }
        const f16* kp = kh + (size_t)(iband + cl) * D + hq * 8;
#pragma unroll 4
        for (int ks = 0; ks < 16; ++ks) {
            const f16x8 kf0 = *(const f16x8*)(kp + ks * 32);
            const f16x8 kf1 = *(const f16x8*)(kp + (size_t)16 * D + ks * 32);
            const f16x8 qf0 = *(const f16x8*)(qbase0 + ks * 64 + qoff);
            const f16x8 qf1 = *(const f16x8*)(qbase1 + ks * 64 + qoff);
            sacc[0][0] = __builtin_amdgcn_mfma_f32_16x16x32_f16(kf0, qf0, sacc[0][0], 0, 0, 0);
            sacc[0][1] = __builtin_amdgcn_mfma_f32_16x16x32_f16(kf1, qf0, sacc[0][1], 0, 0, 0);
            sacc[1][0] = __builtin_amdgcn_mfma_f32_16x16x32_f16(kf0, qf1, sacc[1][0], 0, 0, 0);
            sacc[1][1] = __builtin_amdgcn_mfma_f32_16x16x32_f16(kf1, qf1, sacc[1][1], 0, 0, 0);
        }

        // ---- mask + band stats (band = this wave's 32 i) ----
        // lane holds S^T[i = iband + it2*16 + hq*4 + r][j = j0 + jt*16 + cl]
        float pe[2][2][4], mb[2];
#pragma unroll
        for (int jt = 0; jt < 2; ++jt) {
            const u64 wd = jt ? wd1 : wd0;
            float s[2][4];
#pragma unroll
            for (int it2 = 0; it2 < 2; ++it2)
#pragma unroll
                for (int r = 0; r < 4; ++r)
                    s[it2][r] = ((wd >> (bsh + it2 * 16 + hq * 4 + r)) & 1)
                                ? sacc[jt][it2][r] : NEG;
            float m4 = NEG;
#pragma unroll
            for (int it2 = 0; it2 < 2; ++it2)
#pragma unroll
                for (int r = 0; r < 4; ++r) m4 = fmaxf(m4, s[it2][r]);
            m4 = fmaxf(m4, __shfl_xor(m4, 16, 64));
            m4 = fmaxf(m4, __shfl_xor(m4, 32, 64));
            mb[jt] = m4;
            float pl = 0.f;
#pragma unroll
            for (int it2 = 0; it2 < 2; ++it2)
#pragma unroll
                for (int r = 0; r < 4; ++r) {
                    const float p = (s[it2][r] > -1e29f) ? __expf(s[it2][r] - m4) : 0.f;
                    pe[jt][it2][r] = p;
                    pl += p;
                }
            pl += __shfl_xor(pl, 16, 64);
            pl += __shfl_xor(pl, 32, 64);
            if (l < 16) {
                mlxm[w * 32 + jt * 16 + l] = m4;
                mlxl[w * 32 + jt * 16 + l] = pl;
            }
        }
        __syncthreads();   // A: stats visible

        // ---- combine (wave 0, one j each) ----
        if (t < 32) {
            const float mo = mrow[t];
            const float m0b = mlxm[t],      l0b = mlxl[t];
            const float m1b = mlxm[32 + t], l1b = mlxl[32 + t];
            const float m2b = mlxm[64 + t], l2b = mlxl[64 + t];
            const float m3b = mlxm[96 + t], l3b = mlxl[96 + t];
            const float mn = fmaxf(mo, fmaxf(fmaxf(m0b, m1b), fmaxf(m2b, m3b)));
            const float ln = lrow[t] * __expf(mo - mn)
                           + l0b * __expf(m0b - mn) + l1b * __expf(m1b - mn)
                           + l2b * __expf(m2b - mn) + l3b * __expf(m3b - mn);
            mrow[t] = mn; lrow[t] = ln; scl[t] = __expf(mo - mn);
        }
        __syncthreads();   // B: m_new / scl ready

        // ---- P fix to global max + write to LDS ----
#pragma unroll
        for (int jt = 0; jt < 2; ++jt) {
            const float mn = mrow[jt * 16 + cl];
            const float f  = __expf(mb[jt] - mn);
#pragma unroll
            for (int it2 = 0; it2 < 2; ++it2) {
                union { f16 h[4]; uint2 u; } pc;
#pragma unroll
                for (int r = 0; r < 4; ++r) pc.h[r] = (f16)(pe[jt][it2][r] * f);
                *(uint2*)(Psb + (jt * 16 + cl) * 272 +
                          (w * 32 + it2 * 16 + hq * 4) * 2) = pc.u;
            }
        }

        // ---- rescale O (defer-skip: exact when no row max moved) ----
        {
            const f32x4v sc0 = *(const f32x4v*)(scl + hq * 4);
            const f32x4v sc1 = *(const f32x4v*)(scl + 16 + hq * 4);
            const bool moved = (sc0[0] != 1.f) || (sc0[1] != 1.f) || (sc0[2] != 1.f) ||
                               (sc0[3] != 1.f) || (sc1[0] != 1.f) || (sc1[1] != 1.f) ||
                               (sc1[2] != 1.f) || (sc1[3] != 1.f);
            if (__any(moved)) {
#pragma unroll
                for (int dt = 0; dt < 8; ++dt) {
                    oacc[0][dt][0] *= sc0[0]; oacc[0][dt][1] *= sc0[1];
                    oacc[0][dt][2] *= sc0[2]; oacc[0][dt][3] *= sc0[3];
                    oacc[1][dt][0] *= sc1[0]; oacc[1][dt][1] *= sc1[1];
                    oacc[1][dt][2] *= sc1[2]; oacc[1][dt][3] *= sc1[3];
                }
            }
        }
        __syncthreads();   // C: P ready

        // ---- PV: wave w covers d-band w*128; k over 128 i (4 chunks) ----
        f16x8 pa[2][4];
#pragma unroll
        for (int jt = 0; jt < 2; ++jt)
#pragma unroll
            for (int k2 = 0; k2 < 4; ++k2)
                pa[jt][k2] = *(const f16x8*)(Psb + (jt * 16 + cl) * 272 + k2 * 64 + hq * 16);

#pragma unroll
        for (int dt = 0; dt < 8; ++dt) {
            const f16* vp = vt + (size_t)(w * 128 + dt * 16 + cl) * N + i0t + hq * 8;
#pragma unroll
            for (int k2 = 0; k2 < 4; ++k2) {
                const f16x8 vf = *(const f16x8*)(vp + k2 * 32);
#pragma unroll
                for (int jt = 0; jt < 2; ++jt)
                    oacc[jt][dt] = __builtin_amdgcn_mfma_f32_16x16x32_f16(pa[jt][k2], vf, oacc[jt][dt], 0, 0, 0);
            }
        }
        // (no barrier D: P(t+1) writes are fenced by barriers A/B of t+1)
    }

    // ---- store fp16 unnormalized partial: row j = jt*16+hq*4+r, col = w*128+dt*16+cl ----
#pragma unroll
    for (int jt = 0; jt < 2; ++jt)
#pragma unroll
        for (int dt = 0; dt < 8; ++dt)
#pragma unroll
            for (int r = 0; r < 4; ++r)
                pb[(size_t)(j0 + jt * 16 + hq * 4 + r) * D + w * 128 + dt * 16 + cl] =
                    (f16)oacc[jt][dt][r];
    if (t < 32) {
        float2 v; v.x = mrow[t]; v.y = lrow[t];
        ml[(size_t)ib * N + j0 + t] = v;
    }
}

// ---------------- merge the i-half partials ----------------
__global__ __launch_bounds__(256) void merge_p(
    float* __restrict__ out, const f16* __restrict__ p0,
    const f16* __restrict__ p1, const float2* __restrict__ ml)
{
    const int idx = blockIdx.x * 256 + threadIdx.x;
    const int j = idx >> 7;
    const int col = (idx & 127) * 4;

    const float2 a = ml[j];
    const float2 c = ml[N + j];
    const float m_g = fmaxf(a.x, c.x);
    const float e0 = __expf(a.x - m_g);
    const float e1 = __expf(c.x - m_g);
    const float L  = a.y * e0 + c.y * e1;
    const float inv = (L > 0.f) ? 1.f / L : 0.f;
    const f16x4 h0 = *(const f16x4*)(p0 + (size_t)j * D + col);
    const f16x4 h1 = *(const f16x4*)(p1 + (size_t)j * D + col);
    float4 r;
    r.x = ((float)h0.x * e0 + (float)h1.x * e1) * inv;
    r.y = ((float)h0.y * e0 + (float)h1.y * e1) * inv;
    r.z = ((float)h0.z * e0 + (float)h1.z * e1) * inv;
    r.w = ((float)h0.w * e0 + (float)h1.w * e1) * inv;
    ((float4*)out)[idx] = r;
}

extern "C" void kernel_launch(void* const* d_in, const int* in_sizes, int n_in,
                              void* d_out, int out_size, void* d_ws, size_t ws_size,
                              hipStream_t stream) {
    const float* ns  = (const float*)d_in[0];
    const int*   adj = (const int*)d_in[1];
    const float* Wq  = (const float*)d_in[2];
    const float* Wk  = (const float*)d_in[3];
    const float* Wv  = (const float*)d_in[4];

    char* ws = (char*)d_ws;
    f16*    Xh   = (f16*)(ws + XH_OFF);
    f16*    Wqh  = (f16*)(ws + WQH_OFF);
    f16*    Wkh  = (f16*)(ws + WKH_OFF);
    f16*    Wvh  = (f16*)(ws + WVH_OFF);
    f16*    qh   = (f16*)(ws + QH_OFF);
    f16*    kh   = (f16*)(ws + KH_OFF);
    f16*    vt   = (f16*)(ws + VT_OFF);
    f16*    p0   = (f16*)(ws + XH_OFF);         // overlays dead XH
    f16*    p1   = (f16*)(ws + P1_OFF);
    float2* mlb  = (float2*)(ws + ML_OFF);
    u64*    adjb = (u64*)(ws + ADJ_OFF);
    float*  out  = (float*)d_out;

    cvt_fp16<<<4864, 256, 0, stream>>>(ns, Wq, Wk, Wv, Xh, Wqh, Wkh, Wvh);
    qkv_mfma<<<dim3(4, 64, 3), 256, 0, stream>>>(Xh, Wqh, Wkh, Wvh, qh, kh, vt);
    pack_adj<<<4096, 256, 0, stream>>>(adj, adjb);
    attn_v10<<<512, 256, 0, stream>>>(qh, kh, vt, adjb, p0, p1, mlb);
    merge_p<<<4096, 256, 0, stream>>>(out, p0, p1, mlb);
}

// Round 21
// 434.545 us; speedup vs baseline: 1.4394x; 1.4394x over previous
//
#include <hip/hip_runtime.h>
#include <stdint.h>

#define N 8192
#define D 512
#define NEG -1e30f

typedef _Float16 f16;
typedef f16 f16x4 __attribute__((ext_vector_type(4)));
typedef f16 f16x8 __attribute__((ext_vector_type(8)));
typedef float f32x4v __attribute__((ext_vector_type(4)));
typedef float f32x16 __attribute__((ext_vector_type(16)));
typedef unsigned long long u64;

// ---- workspace layout (bytes) ----
#define XH_OFF   0ull
#define WQH_OFF  (XH_OFF + 8192ull * 512 * 2)
#define WKH_OFF  (WQH_OFF + 512ull * 512 * 2)
#define WVH_OFF  (WKH_OFF + 512ull * 512 * 2)
#define QH_OFF   (WVH_OFF + 512ull * 512 * 2)
#define KH_OFF   (QH_OFF + 8192ull * 512 * 2)
#define VT_OFF   (KH_OFF + 8192ull * 512 * 2)
#define PART_SZ  (8192ull * 512 * 2)                // one fp16 partial, 8 MB
#define P123_OFF (VT_OFF + 8192ull * 512 * 2)
#define ML_SZ    (4ull * N * 8)                     // float2[4][N]
#define ADJ_SZ   (128ull * N * 8)                   // u64 bitmap, 8 MB

// ---- attn LDS map (78,592 B -> 2 blocks/CU) ----
#define QROW     1040
#define QS_OFF   0
#define PROW     144
#define PSB_OFF  66560            // 64 * 1040
#define MLXM_OFF (PSB_OFF + 64 * PROW)      // 75776, [4][64] f32
#define MLXL_OFF (MLXM_OFF + 1024)          // 76800
#define MROW_OFF (MLXL_OFF + 1024)          // 77824
#define LROW_OFF (MROW_OFF + 256)           // 78080
#define SCL_OFF  (LROW_OFF + 256)           // 78336
#define LDSB_V4  (SCL_OFF + 256)            // 78592

// ---------------- fp32 -> fp16 conversion ----------------
__global__ __launch_bounds__(256) void cvt_fp16(
    const float* __restrict__ X,
    const float* __restrict__ Wq, const float* __restrict__ Wk, const float* __restrict__ Wv,
    f16* __restrict__ Xh,
    f16* __restrict__ Wqh, f16* __restrict__ Wkh, f16* __restrict__ Wvh)
{
    const int idx = blockIdx.x * 256 + threadIdx.x;
    const float* src; f16* dst; int off;
    if (idx < 1048576)      { src = X;  dst = Xh;  off = idx; }
    else if (idx < 1114112) { src = Wq; dst = Wqh; off = idx - 1048576; }
    else if (idx < 1179648) { src = Wk; dst = Wkh; off = idx - 1114112; }
    else                    { src = Wv; dst = Wvh; off = idx - 1179648; }
    const float4 v = ((const float4*)src)[off];
    f16x4 h; h.x = (f16)v.x; h.y = (f16)v.y; h.z = (f16)v.z; h.w = (f16)v.w;
    *(f16x4*)(dst + (size_t)off * 4) = h;
}

// ---------------- QKV via MFMA (unchanged) ----------------
__global__ __launch_bounds__(256) void qkv_mfma(
    const f16* __restrict__ Xh,
    const f16* __restrict__ Wqh, const f16* __restrict__ Wkh, const f16* __restrict__ Wvh,
    f16* __restrict__ qh, f16* __restrict__ kh, f16* __restrict__ vt)
{
    const int t    = threadIdx.x;
    const int w    = t >> 6;
    const int lane = t & 63;
    const int lo   = lane & 31;
    const int hi   = lane >> 5;
    const int z    = blockIdx.z;

    int m0, c0; const f16 *Ap, *Bp; f16* Yp; size_t ldy;
    if (z == 2) {
        m0 = blockIdx.x * 128 + w * 32; c0 = blockIdx.y * 128;
        Ap = Wvh; Bp = Xh; Yp = vt; ldy = N;
    } else {
        m0 = blockIdx.y * 128 + w * 32; c0 = blockIdx.x * 128;
        Ap = Xh; Bp = z ? Wkh : Wqh; Yp = z ? kh : qh; ldy = D;
    }

    const f16* arow = Ap + (size_t)(m0 + lo) * D + hi * 8;
    const f16* brow[4];
#pragma unroll
    for (int nn = 0; nn < 4; ++nn)
        brow[nn] = Bp + (size_t)(c0 + nn * 32 + lo) * D + hi * 8;

    f32x16 acc[4];
#pragma unroll
    for (int nn = 0; nn < 4; ++nn)
#pragma unroll
        for (int e = 0; e < 16; ++e) acc[nn][e] = 0.f;

#pragma unroll 4
    for (int ks = 0; ks < 32; ++ks) {
        const f16x8 a = *(const f16x8*)(arow + ks * 16);
#pragma unroll
        for (int nn = 0; nn < 4; ++nn) {
            const f16x8 b = *(const f16x8*)(brow[nn] + ks * 16);
            acc[nn] = __builtin_amdgcn_mfma_f32_32x32x16_f16(a, b, acc[nn], 0, 0, 0);
        }
    }

#pragma unroll
    for (int nn = 0; nn < 4; ++nn)
#pragma unroll
        for (int r = 0; r < 16; ++r) {
            const int row = m0 + (r & 3) + 8 * (r >> 2) + 4 * hi;
            Yp[(size_t)row * ldy + c0 + nn * 32 + lo] = (f16)acc[nn][r];
        }
}

// ---------------- adjacency bit-pack, COALESCED (r13) ----------------
// adjb[iw][j] bit b = adj[iw*64+b][j]
__global__ __launch_bounds__(256) void pack_adj(
    const int* __restrict__ adj, u64* __restrict__ adjb)
{
    const int idx = blockIdx.x * 256 + threadIdx.x;   // 1,048,576 total
    const int j   = idx & (N - 1);
    const int iw  = idx >> 13;                        // 0..127
    const int* src = adj + (size_t)iw * 64 * N + j;
    u64 bits = 0;
#pragma unroll 8
    for (int i2 = 0; i2 < 64; ++i2)
        bits |= (u64)(src[(size_t)i2 * N] != 0) << i2;
    adjb[(size_t)iw * N + j] = bits;
}

// ---------------- attention v4.5: r19 champion + s_setprio around MFMA clusters ----------------
// grid = 128 j-tiles (BJ=64) x nib i-blocks. Block: 256 thr / 4 waves, 2/CU.
// Byte-identical to the 432-us r19 kernel except setprio(1)/(0) brackets the
// QK and PV MFMA clusters (T5): with 2 desynchronized blocks/CU, the scheduler
// prefers the MFMA-issuing wave over the softmax-VALU wave when both are ready.
__global__ __launch_bounds__(256, 2) void attn_v4(
    const f16* __restrict__ qh, const f16* __restrict__ kh,
    const f16* __restrict__ vt, const u64* __restrict__ adjb,
    f16* __restrict__ part0, f16* __restrict__ part123, float2* __restrict__ ml)
{
    extern __shared__ char smem[];
    char*  Qs   = smem + QS_OFF;
    char*  Psb  = smem + PSB_OFF;
    float* mlxm = (float*)(smem + MLXM_OFF);
    float* mlxl = (float*)(smem + MLXL_OFF);
    float* mrow = (float*)(smem + MROW_OFF);
    float* lrow = (float*)(smem + LROW_OFF);
    float* scl  = (float*)(smem + SCL_OFF);

    const int t  = threadIdx.x;
    const int w  = t >> 6;
    const int l  = t & 63;
    const int cl = l & 15;     // mfma column lane
    const int hq = l >> 4;     // k-group / row-quad

    // XCD-aware mapping: i-block pinned per XCD group, bijective j-tile
    const int nib = gridDim.x >> 7;          // 4 or 2
    const int b   = blockIdx.x;
    const int xcd = b & 7;
    int ib, jt_;
    if (nib == 4) { ib = xcd >> 1; jt_ = (xcd & 1) * 64 + (b >> 3); }
    else          { ib = xcd >> 2; jt_ = (xcd & 3) * 32 + (b >> 3); }
    const int j0    = jt_ * 64;
    const int ibase = ib * (N / nib);
    const int iters = (N / nib) >> 6;

    f16* pb = (ib == 0) ? part0 : part123 + (size_t)(ib - 1) * ((size_t)N * D);

    // ---- stage Q[j0..j0+63][*] into Qs (row stride 1040) ----
    for (int c = t; c < 64 * 64; c += 256) {
        const int row = c >> 6, off = c & 63;
        f16x8 v = *(const f16x8*)(qh + (size_t)(j0 + row) * D + off * 8);
        *(f16x8*)(Qs + row * QROW + off * 16) = v;
    }
    if (t < 64) { mrow[t] = NEG; lrow[t] = 0.f; }
    __syncthreads();

    f32x4v oacc[4][8];
#pragma unroll
    for (int jt = 0; jt < 4; ++jt)
#pragma unroll
        for (int dt = 0; dt < 8; ++dt) {
            oacc[jt][dt][0] = 0.f; oacc[jt][dt][1] = 0.f;
            oacc[jt][dt][2] = 0.f; oacc[jt][dt][3] = 0.f;
        }

    // per-wave invariant bases
    const char* qbase[4];
#pragma unroll
    for (int jt = 0; jt < 4; ++jt) qbase[jt] = Qs + (jt * 16 + cl) * QROW;
    const int qoff = hq * 16;

    for (int it = 0; it < iters; ++it) {
        const int i0t = ibase + it * 64;

        // ---- mask bitmap: 4 coalesced u64 loads (latency hidden under QK) ----
        u64 wd[4];
        {
            const u64* ab = adjb + ((size_t)(i0t >> 6)) * N + j0 + cl;
#pragma unroll
            for (int jt = 0; jt < 4; ++jt) wd[jt] = ab[jt * 16];
        }

        // ---- QK^T: wave w covers i-band w*16..+15 ----
        f32x4v sacc[4];
#pragma unroll
        for (int jt = 0; jt < 4; ++jt) {
            sacc[jt][0] = 0.f; sacc[jt][1] = 0.f; sacc[jt][2] = 0.f; sacc[jt][3] = 0.f;
        }
        const f16* kp = kh + (size_t)(i0t + w * 16 + cl) * D + hq * 8;
        __builtin_amdgcn_s_setprio(1);
#pragma unroll 4
        for (int ks = 0; ks < 16; ++ks) {
            const f16x8 kf = *(const f16x8*)(kp + ks * 32);
#pragma unroll
            for (int jt = 0; jt < 4; ++jt) {
                const f16x8 qf = *(const f16x8*)(qbase[jt] + ks * 64 + qoff);
                sacc[jt] = __builtin_amdgcn_mfma_f32_16x16x32_f16(kf, qf, sacc[jt], 0, 0, 0);
            }
        }
        __builtin_amdgcn_s_setprio(0);

        // ---- mask + band stats (band = this wave's 16 i) ----
        // lane holds S^T[i = i0t + w*16 + hq*4 + r][j = j0 + jt*16 + cl]
        float pe[4][4], mb[4];
#pragma unroll
        for (int jt = 0; jt < 4; ++jt) {
            const uint32_t sub = (uint32_t)(wd[jt] >> (w * 16 + hq * 4)) & 0xFu;
            float s[4];
#pragma unroll
            for (int r = 0; r < 4; ++r) s[r] = ((sub >> r) & 1) ? sacc[jt][r] : NEG;
            float m4 = fmaxf(fmaxf(s[0], s[1]), fmaxf(s[2], s[3]));
            m4 = fmaxf(m4, __shfl_xor(m4, 16, 64));
            m4 = fmaxf(m4, __shfl_xor(m4, 32, 64));
            mb[jt] = m4;
            float pl = 0.f;
#pragma unroll
            for (int r = 0; r < 4; ++r) {
                const float p = (s[r] > -1e29f) ? __expf(s[r] - m4) : 0.f;
                pe[jt][r] = p;
                pl += p;
            }
            pl += __shfl_xor(pl, 16, 64);
            pl += __shfl_xor(pl, 32, 64);
            if (l < 16) {
                mlxm[w * 64 + jt * 16 + l] = m4;
                mlxl[w * 64 + jt * 16 + l] = pl;
            }
        }
        __syncthreads();   // A: stats visible

        // ---- combine (wave 0, one j each) ----
        if (t < 64) {
            const float mo = mrow[t];
            const float m0b = mlxm[t],       l0b = mlxl[t];
            const float m1b = mlxm[64 + t],  l1b = mlxl[64 + t];
            const float m2b = mlxm[128 + t], l2b = mlxl[128 + t];
            const float m3b = mlxm[192 + t], l3b = mlxl[192 + t];
            const float mn = fmaxf(mo, fmaxf(fmaxf(m0b, m1b), fmaxf(m2b, m3b)));
            const float ln = lrow[t] * __expf(mo - mn)
                           + l0b * __expf(m0b - mn) + l1b * __expf(m1b - mn)
                           + l2b * __expf(m2b - mn) + l3b * __expf(m3b - mn);
            mrow[t] = mn; lrow[t] = ln; scl[t] = __expf(mo - mn);
        }
        __syncthreads();   // B: m_new / scl ready

        // ---- rescale O, fix P to global max, write P to LDS ----
#pragma unroll
        for (int jt = 0; jt < 4; ++jt) {
            const f32x4v sc4 = *(const f32x4v*)(scl + jt * 16 + hq * 4);
#pragma unroll
            for (int dt = 0; dt < 8; ++dt) {
                oacc[jt][dt][0] *= sc4[0]; oacc[jt][dt][1] *= sc4[1];
                oacc[jt][dt][2] *= sc4[2]; oacc[jt][dt][3] *= sc4[3];
            }
            const float mn = mrow[jt * 16 + cl];
            const float f  = __expf(mb[jt] - mn);
            union { f16 h[4]; uint2 u; } pc;
#pragma unroll
            for (int r = 0; r < 4; ++r) pc.h[r] = (f16)(pe[jt][r] * f);
            *(uint2*)(Psb + (jt * 16 + cl) * PROW + (w * 16 + hq * 4) * 2) = pc.u;
        }
        __syncthreads();   // C: P ready

        // ---- PV: wave w covers d-band w*128..+127 (fully static unroll) ----
        f16x8 pa[4][2];
#pragma unroll
        for (int jt = 0; jt < 4; ++jt)
#pragma unroll
            for (int k2 = 0; k2 < 2; ++k2)
                pa[jt][k2] = *(const f16x8*)(Psb + (jt * 16 + cl) * PROW + k2 * 64 + hq * 16);

        __builtin_amdgcn_s_setprio(1);
#pragma unroll
        for (int dt = 0; dt < 8; ++dt) {
            const f16* vp = vt + (size_t)(w * 128 + dt * 16 + cl) * N + i0t + hq * 8;
#pragma unroll
            for (int k2 = 0; k2 < 2; ++k2) {
                const f16x8 vf = *(const f16x8*)(vp + k2 * 32);
#pragma unroll
                for (int jt = 0; jt < 4; ++jt)
                    oacc[jt][dt] = __builtin_amdgcn_mfma_f32_16x16x32_f16(pa[jt][k2], vf, oacc[jt][dt], 0, 0, 0);
            }
        }
        __builtin_amdgcn_s_setprio(0);
        // (no barrier D: PV(t) reads are fenced from P(t+1) writes by A/B of t+1)
    }

    // ---- store fp16 unnormalized partial: C[row=j][col=d] ----
#pragma unroll
    for (int jt = 0; jt < 4; ++jt)
#pragma unroll
        for (int dt = 0; dt < 8; ++dt)
#pragma unroll
            for (int r = 0; r < 4; ++r)
                pb[(size_t)(j0 + jt * 16 + hq * 4 + r) * D + w * 128 + dt * 16 + cl] =
                    (f16)oacc[jt][dt][r];
    if (t < 64) {
        float2 v; v.x = mrow[t]; v.y = lrow[t];
        ml[(size_t)ib * N + j0 + t] = v;
    }
}

// ---------------- merge the i-block partials ----------------
__global__ __launch_bounds__(256) void merge_p(
    float* __restrict__ out, const f16* __restrict__ p0,
    const f16* __restrict__ p123, const float2* __restrict__ ml, int nib)
{
    const int idx = blockIdx.x * 256 + threadIdx.x;
    const int j = idx >> 7;
    const int col = (idx & 127) * 4;

    float m_g = NEG;
    for (int ib = 0; ib < nib; ++ib) m_g = fmaxf(m_g, ml[(size_t)ib * N + j].x);
    float L = 0.f;
    float4 acc; acc.x = 0.f; acc.y = 0.f; acc.z = 0.f; acc.w = 0.f;
    for (int ib = 0; ib < nib; ++ib) {
        const float2 a = ml[(size_t)ib * N + j];
        const float e = __expf(a.x - m_g);
        L += e * a.y;
        const f16* pp = (ib == 0) ? p0 : p123 + (size_t)(ib - 1) * ((size_t)N * D);
        const f16x4 h = *(const f16x4*)(pp + (size_t)j * D + col);
        acc.x += e * (float)h.x; acc.y += e * (float)h.y;
        acc.z += e * (float)h.z; acc.w += e * (float)h.w;
    }
    const float inv = (L > 0.f) ? 1.f / L : 0.f;
    float4 r; r.x = acc.x * inv; r.y = acc.y * inv; r.z = acc.z * inv; r.w = acc.w * inv;
    ((float4*)out)[idx] = r;
}

extern "C" void kernel_launch(void* const* d_in, const int* in_sizes, int n_in,
                              void* d_out, int out_size, void* d_ws, size_t ws_size,
                              hipStream_t stream) {
    const float* ns  = (const float*)d_in[0];
    const int*   adj = (const int*)d_in[1];
    const float* Wq  = (const float*)d_in[2];
    const float* Wk  = (const float*)d_in[3];
    const float* Wv  = (const float*)d_in[4];

    char* ws = (char*)d_ws;
    f16*   Xh   = (f16*)(ws + XH_OFF);
    f16*   Wqh  = (f16*)(ws + WQH_OFF);
    f16*   Wkh  = (f16*)(ws + WKH_OFF);
    f16*   Wvh  = (f16*)(ws + WVH_OFF);
    f16*   qh   = (f16*)(ws + QH_OFF);
    f16*   kh   = (f16*)(ws + KH_OFF);
    f16*   vt   = (f16*)(ws + VT_OFF);
    f16*   p0   = (f16*)(ws + XH_OFF);          // overlays dead XH
    f16*   p123 = (f16*)(ws + P123_OFF);
    float* out  = (float*)d_out;

    const size_t need4 = P123_OFF + 3 * PART_SZ + ML_SZ + ADJ_SZ;
    int nib; size_t ml_off;
    if (ws_size >= need4) { nib = 4; ml_off = P123_OFF + 3 * PART_SZ; }
    else                  { nib = 2; ml_off = P123_OFF + 1 * PART_SZ; }
    float2* mlb  = (float2*)(ws + ml_off);
    u64*    adjb = (u64*)(ws + ml_off + ML_SZ);

    (void)hipFuncSetAttribute((const void*)attn_v4,
                              hipFuncAttributeMaxDynamicSharedMemorySize, LDSB_V4);

    cvt_fp16<<<4864, 256, 0, stream>>>(ns, Wq, Wk, Wv, Xh, Wqh, Wkh, Wvh);
    qkv_mfma<<<dim3(4, 64, 3), 256, 0, stream>>>(Xh, Wqh, Wkh, Wvh, qh, kh, vt);
    pack_adj<<<4096, 256, 0, stream>>>(adj, adjb);
    attn_v4<<<128 * nib, 256, LDSB_V4, stream>>>(qh, kh, vt, adjb, p0, p123, mlb);
    merge_p<<<4096, 256, 0, stream>>>(out, p0, p123, mlb, nib);
}

// Round 22
// 431.591 us; speedup vs baseline: 1.4493x; 1.0068x over previous
//
#include <hip/hip_runtime.h>
#include <stdint.h>

#define N 8192
#define D 512
#define NEG -1e30f

typedef _Float16 f16;
typedef f16 f16x4 __attribute__((ext_vector_type(4)));
typedef f16 f16x8 __attribute__((ext_vector_type(8)));
typedef float f32x4v __attribute__((ext_vector_type(4)));
typedef float f32x16 __attribute__((ext_vector_type(16)));
typedef unsigned long long u64;

// ---- workspace layout (bytes) ----
#define XH_OFF   0ull
#define WQH_OFF  (XH_OFF + 8192ull * 512 * 2)
#define WKH_OFF  (WQH_OFF + 512ull * 512 * 2)
#define WVH_OFF  (WKH_OFF + 512ull * 512 * 2)
#define QH_OFF   (WVH_OFF + 512ull * 512 * 2)
#define KH_OFF   (QH_OFF + 8192ull * 512 * 2)
#define VT_OFF   (KH_OFF + 8192ull * 512 * 2)
#define PART_SZ  (8192ull * 512 * 2)                // one fp16 partial, 8 MB
#define P123_OFF (VT_OFF + 8192ull * 512 * 2)
#define ML_SZ    (4ull * N * 8)                     // float2[4][N]
#define ADJ_SZ   (128ull * N * 8)                   // u64 bitmap, 8 MB

// ---- attn LDS map (78,592 B -> 2 blocks/CU) ----
#define QROW     1040
#define QS_OFF   0
#define PROW     144
#define PSB_OFF  66560            // 64 * 1040
#define MLXM_OFF (PSB_OFF + 64 * PROW)      // 75776, [4][64] f32
#define MLXL_OFF (MLXM_OFF + 1024)          // 76800
#define MROW_OFF (MLXL_OFF + 1024)          // 77824
#define LROW_OFF (MROW_OFF + 256)           // 78080
#define SCL_OFF  (LROW_OFF + 256)           // 78336
#define LDSB_V4  (SCL_OFF + 256)            // 78592

// ---------------- fp32 -> fp16 conversion ----------------
__global__ __launch_bounds__(256) void cvt_fp16(
    const float* __restrict__ X,
    const float* __restrict__ Wq, const float* __restrict__ Wk, const float* __restrict__ Wv,
    f16* __restrict__ Xh,
    f16* __restrict__ Wqh, f16* __restrict__ Wkh, f16* __restrict__ Wvh)
{
    const int idx = blockIdx.x * 256 + threadIdx.x;
    const float* src; f16* dst; int off;
    if (idx < 1048576)      { src = X;  dst = Xh;  off = idx; }
    else if (idx < 1114112) { src = Wq; dst = Wqh; off = idx - 1048576; }
    else if (idx < 1179648) { src = Wk; dst = Wkh; off = idx - 1114112; }
    else                    { src = Wv; dst = Wvh; off = idx - 1179648; }
    const float4 v = ((const float4*)src)[off];
    f16x4 h; h.x = (f16)v.x; h.y = (f16)v.y; h.z = (f16)v.z; h.w = (f16)v.w;
    *(f16x4*)(dst + (size_t)off * 4) = h;
}

// ---------------- QKV via MFMA (unchanged) ----------------
__global__ __launch_bounds__(256) void qkv_mfma(
    const f16* __restrict__ Xh,
    const f16* __restrict__ Wqh, const f16* __restrict__ Wkh, const f16* __restrict__ Wvh,
    f16* __restrict__ qh, f16* __restrict__ kh, f16* __restrict__ vt)
{
    const int t    = threadIdx.x;
    const int w    = t >> 6;
    const int lane = t & 63;
    const int lo   = lane & 31;
    const int hi   = lane >> 5;
    const int z    = blockIdx.z;

    int m0, c0; const f16 *Ap, *Bp; f16* Yp; size_t ldy;
    if (z == 2) {
        m0 = blockIdx.x * 128 + w * 32; c0 = blockIdx.y * 128;
        Ap = Wvh; Bp = Xh; Yp = vt; ldy = N;
    } else {
        m0 = blockIdx.y * 128 + w * 32; c0 = blockIdx.x * 128;
        Ap = Xh; Bp = z ? Wkh : Wqh; Yp = z ? kh : qh; ldy = D;
    }

    const f16* arow = Ap + (size_t)(m0 + lo) * D + hi * 8;
    const f16* brow[4];
#pragma unroll
    for (int nn = 0; nn < 4; ++nn)
        brow[nn] = Bp + (size_t)(c0 + nn * 32 + lo) * D + hi * 8;

    f32x16 acc[4];
#pragma unroll
    for (int nn = 0; nn < 4; ++nn)
#pragma unroll
        for (int e = 0; e < 16; ++e) acc[nn][e] = 0.f;

#pragma unroll 4
    for (int ks = 0; ks < 32; ++ks) {
        const f16x8 a = *(const f16x8*)(arow + ks * 16);
#pragma unroll
        for (int nn = 0; nn < 4; ++nn) {
            const f16x8 b = *(const f16x8*)(brow[nn] + ks * 16);
            acc[nn] = __builtin_amdgcn_mfma_f32_32x32x16_f16(a, b, acc[nn], 0, 0, 0);
        }
    }

#pragma unroll
    for (int nn = 0; nn < 4; ++nn)
#pragma unroll
        for (int r = 0; r < 16; ++r) {
            const int row = m0 + (r & 3) + 8 * (r >> 2) + 4 * hi;
            Yp[(size_t)row * ldy + c0 + nn * 32 + lo] = (f16)acc[nn][r];
        }
}

// ---------------- adjacency bit-pack, COALESCED (r13) ----------------
// adjb[iw][j] bit b = adj[iw*64+b][j]
__global__ __launch_bounds__(256) void pack_adj(
    const int* __restrict__ adj, u64* __restrict__ adjb)
{
    const int idx = blockIdx.x * 256 + threadIdx.x;   // 1,048,576 total
    const int j   = idx & (N - 1);
    const int iw  = idx >> 13;                        // 0..127
    const int* src = adj + (size_t)iw * 64 * N + j;
    u64 bits = 0;
#pragma unroll 8
    for (int i2 = 0; i2 < 64; ++i2)
        bits |= (u64)(src[(size_t)i2 * N] != 0) << i2;
    adjb[(size_t)iw * N + j] = bits;
}

// ---------------- attention v4.4 (champion): bitmap mask + 3 barriers/tile ----------------
// grid = 128 j-tiles (BJ=64) x nib i-blocks. Block: 256 thr / 4 waves, 2/CU.
// Per tile (BI=64): QK^T waves split i-bands (w*16); PV waves split d-bands
// (w*128). Bitmap mask: 4 coalesced u64 loads per lane at loop head (latency
// hidden under QK's 64 MFMAs). Barrier D deleted (P(t+1) writes fenced by
// A/B of t+1). NO register prefetch and NO setprio (both measured negative:
// prefetch spills at the 252/256 unified-register budget; setprio inverts
// priority between the 2 co-resident blocks).
__global__ __launch_bounds__(256, 2) void attn_v4(
    const f16* __restrict__ qh, const f16* __restrict__ kh,
    const f16* __restrict__ vt, const u64* __restrict__ adjb,
    f16* __restrict__ part0, f16* __restrict__ part123, float2* __restrict__ ml)
{
    extern __shared__ char smem[];
    char*  Qs   = smem + QS_OFF;
    char*  Psb  = smem + PSB_OFF;
    float* mlxm = (float*)(smem + MLXM_OFF);
    float* mlxl = (float*)(smem + MLXL_OFF);
    float* mrow = (float*)(smem + MROW_OFF);
    float* lrow = (float*)(smem + LROW_OFF);
    float* scl  = (float*)(smem + SCL_OFF);

    const int t  = threadIdx.x;
    const int w  = t >> 6;
    const int l  = t & 63;
    const int cl = l & 15;     // mfma column lane
    const int hq = l >> 4;     // k-group / row-quad

    // XCD-aware mapping: i-block pinned per XCD group, bijective j-tile
    const int nib = gridDim.x >> 7;          // 4 or 2
    const int b   = blockIdx.x;
    const int xcd = b & 7;
    int ib, jt_;
    if (nib == 4) { ib = xcd >> 1; jt_ = (xcd & 1) * 64 + (b >> 3); }
    else          { ib = xcd >> 2; jt_ = (xcd & 3) * 32 + (b >> 3); }
    const int j0    = jt_ * 64;
    const int ibase = ib * (N / nib);
    const int iters = (N / nib) >> 6;

    f16* pb = (ib == 0) ? part0 : part123 + (size_t)(ib - 1) * ((size_t)N * D);

    // ---- stage Q[j0..j0+63][*] into Qs (row stride 1040) ----
    for (int c = t; c < 64 * 64; c += 256) {
        const int row = c >> 6, off = c & 63;
        f16x8 v = *(const f16x8*)(qh + (size_t)(j0 + row) * D + off * 8);
        *(f16x8*)(Qs + row * QROW + off * 16) = v;
    }
    if (t < 64) { mrow[t] = NEG; lrow[t] = 0.f; }
    __syncthreads();

    f32x4v oacc[4][8];
#pragma unroll
    for (int jt = 0; jt < 4; ++jt)
#pragma unroll
        for (int dt = 0; dt < 8; ++dt) {
            oacc[jt][dt][0] = 0.f; oacc[jt][dt][1] = 0.f;
            oacc[jt][dt][2] = 0.f; oacc[jt][dt][3] = 0.f;
        }

    // per-wave invariant bases
    const char* qbase[4];
#pragma unroll
    for (int jt = 0; jt < 4; ++jt) qbase[jt] = Qs + (jt * 16 + cl) * QROW;
    const int qoff = hq * 16;

    for (int it = 0; it < iters; ++it) {
        const int i0t = ibase + it * 64;

        // ---- mask bitmap: 4 coalesced u64 loads (latency hidden under QK) ----
        u64 wd[4];
        {
            const u64* ab = adjb + ((size_t)(i0t >> 6)) * N + j0 + cl;
#pragma unroll
            for (int jt = 0; jt < 4; ++jt) wd[jt] = ab[jt * 16];
        }

        // ---- QK^T: wave w covers i-band w*16..+15 ----
        f32x4v sacc[4];
#pragma unroll
        for (int jt = 0; jt < 4; ++jt) {
            sacc[jt][0] = 0.f; sacc[jt][1] = 0.f; sacc[jt][2] = 0.f; sacc[jt][3] = 0.f;
        }
        const f16* kp = kh + (size_t)(i0t + w * 16 + cl) * D + hq * 8;
#pragma unroll 4
        for (int ks = 0; ks < 16; ++ks) {
            const f16x8 kf = *(const f16x8*)(kp + ks * 32);
#pragma unroll
            for (int jt = 0; jt < 4; ++jt) {
                const f16x8 qf = *(const f16x8*)(qbase[jt] + ks * 64 + qoff);
                sacc[jt] = __builtin_amdgcn_mfma_f32_16x16x32_f16(kf, qf, sacc[jt], 0, 0, 0);
            }
        }

        // ---- mask + band stats (band = this wave's 16 i) ----
        // lane holds S^T[i = i0t + w*16 + hq*4 + r][j = j0 + jt*16 + cl]
        float pe[4][4], mb[4];
#pragma unroll
        for (int jt = 0; jt < 4; ++jt) {
            const uint32_t sub = (uint32_t)(wd[jt] >> (w * 16 + hq * 4)) & 0xFu;
            float s[4];
#pragma unroll
            for (int r = 0; r < 4; ++r) s[r] = ((sub >> r) & 1) ? sacc[jt][r] : NEG;
            float m4 = fmaxf(fmaxf(s[0], s[1]), fmaxf(s[2], s[3]));
            m4 = fmaxf(m4, __shfl_xor(m4, 16, 64));
            m4 = fmaxf(m4, __shfl_xor(m4, 32, 64));
            mb[jt] = m4;
            float pl = 0.f;
#pragma unroll
            for (int r = 0; r < 4; ++r) {
                const float p = (s[r] > -1e29f) ? __expf(s[r] - m4) : 0.f;
                pe[jt][r] = p;
                pl += p;
            }
            pl += __shfl_xor(pl, 16, 64);
            pl += __shfl_xor(pl, 32, 64);
            if (l < 16) {
                mlxm[w * 64 + jt * 16 + l] = m4;
                mlxl[w * 64 + jt * 16 + l] = pl;
            }
        }
        __syncthreads();   // A: stats visible

        // ---- combine (wave 0, one j each) ----
        if (t < 64) {
            const float mo = mrow[t];
            const float m0b = mlxm[t],       l0b = mlxl[t];
            const float m1b = mlxm[64 + t],  l1b = mlxl[64 + t];
            const float m2b = mlxm[128 + t], l2b = mlxl[128 + t];
            const float m3b = mlxm[192 + t], l3b = mlxl[192 + t];
            const float mn = fmaxf(mo, fmaxf(fmaxf(m0b, m1b), fmaxf(m2b, m3b)));
            const float ln = lrow[t] * __expf(mo - mn)
                           + l0b * __expf(m0b - mn) + l1b * __expf(m1b - mn)
                           + l2b * __expf(m2b - mn) + l3b * __expf(m3b - mn);
            mrow[t] = mn; lrow[t] = ln; scl[t] = __expf(mo - mn);
        }
        __syncthreads();   // B: m_new / scl ready

        // ---- rescale O, fix P to global max, write P to LDS ----
#pragma unroll
        for (int jt = 0; jt < 4; ++jt) {
            const f32x4v sc4 = *(const f32x4v*)(scl + jt * 16 + hq * 4);
#pragma unroll
            for (int dt = 0; dt < 8; ++dt) {
                oacc[jt][dt][0] *= sc4[0]; oacc[jt][dt][1] *= sc4[1];
                oacc[jt][dt][2] *= sc4[2]; oacc[jt][dt][3] *= sc4[3];
            }
            const float mn = mrow[jt * 16 + cl];
            const float f  = __expf(mb[jt] - mn);
            union { f16 h[4]; uint2 u; } pc;
#pragma unroll
            for (int r = 0; r < 4; ++r) pc.h[r] = (f16)(pe[jt][r] * f);
            *(uint2*)(Psb + (jt * 16 + cl) * PROW + (w * 16 + hq * 4) * 2) = pc.u;
        }
        __syncthreads();   // C: P ready

        // ---- PV: wave w covers d-band w*128..+127 (fully static unroll) ----
        f16x8 pa[4][2];
#pragma unroll
        for (int jt = 0; jt < 4; ++jt)
#pragma unroll
            for (int k2 = 0; k2 < 2; ++k2)
                pa[jt][k2] = *(const f16x8*)(Psb + (jt * 16 + cl) * PROW + k2 * 64 + hq * 16);

#pragma unroll
        for (int dt = 0; dt < 8; ++dt) {
            const f16* vp = vt + (size_t)(w * 128 + dt * 16 + cl) * N + i0t + hq * 8;
#pragma unroll
            for (int k2 = 0; k2 < 2; ++k2) {
                const f16x8 vf = *(const f16x8*)(vp + k2 * 32);
#pragma unroll
                for (int jt = 0; jt < 4; ++jt)
                    oacc[jt][dt] = __builtin_amdgcn_mfma_f32_16x16x32_f16(pa[jt][k2], vf, oacc[jt][dt], 0, 0, 0);
            }
        }
        // (no barrier D: PV(t) reads are fenced from P(t+1) writes by A/B of t+1)
    }

    // ---- store fp16 unnormalized partial: C[row=j][col=d] ----
#pragma unroll
    for (int jt = 0; jt < 4; ++jt)
#pragma unroll
        for (int dt = 0; dt < 8; ++dt)
#pragma unroll
            for (int r = 0; r < 4; ++r)
                pb[(size_t)(j0 + jt * 16 + hq * 4 + r) * D + w * 128 + dt * 16 + cl] =
                    (f16)oacc[jt][dt][r];
    if (t < 64) {
        float2 v; v.x = mrow[t]; v.y = lrow[t];
        ml[(size_t)ib * N + j0 + t] = v;
    }
}

// ---------------- merge the i-block partials ----------------
__global__ __launch_bounds__(256) void merge_p(
    float* __restrict__ out, const f16* __restrict__ p0,
    const f16* __restrict__ p123, const float2* __restrict__ ml, int nib)
{
    const int idx = blockIdx.x * 256 + threadIdx.x;
    const int j = idx >> 7;
    const int col = (idx & 127) * 4;

    float m_g = NEG;
    for (int ib = 0; ib < nib; ++ib) m_g = fmaxf(m_g, ml[(size_t)ib * N + j].x);
    float L = 0.f;
    float4 acc; acc.x = 0.f; acc.y = 0.f; acc.z = 0.f; acc.w = 0.f;
    for (int ib = 0; ib < nib; ++ib) {
        const float2 a = ml[(size_t)ib * N + j];
        const float e = __expf(a.x - m_g);
        L += e * a.y;
        const f16* pp = (ib == 0) ? p0 : p123 + (size_t)(ib - 1) * ((size_t)N * D);
        const f16x4 h = *(const f16x4*)(pp + (size_t)j * D + col);
        acc.x += e * (float)h.x; acc.y += e * (float)h.y;
        acc.z += e * (float)h.z; acc.w += e * (float)h.w;
    }
    const float inv = (L > 0.f) ? 1.f / L : 0.f;
    float4 r; r.x = acc.x * inv; r.y = acc.y * inv; r.z = acc.z * inv; r.w = acc.w * inv;
    ((float4*)out)[idx] = r;
}

extern "C" void kernel_launch(void* const* d_in, const int* in_sizes, int n_in,
                              void* d_out, int out_size, void* d_ws, size_t ws_size,
                              hipStream_t stream) {
    const float* ns  = (const float*)d_in[0];
    const int*   adj = (const int*)d_in[1];
    const float* Wq  = (const float*)d_in[2];
    const float* Wk  = (const float*)d_in[3];
    const float* Wv  = (const float*)d_in[4];

    char* ws = (char*)d_ws;
    f16*   Xh   = (f16*)(ws + XH_OFF);
    f16*   Wqh  = (f16*)(ws + WQH_OFF);
    f16*   Wkh  = (f16*)(ws + WKH_OFF);
    f16*   Wvh  = (f16*)(ws + WVH_OFF);
    f16*   qh   = (f16*)(ws + QH_OFF);
    f16*   kh   = (f16*)(ws + KH_OFF);
    f16*   vt   = (f16*)(ws + VT_OFF);
    f16*   p0   = (f16*)(ws + XH_OFF);          // overlays dead XH
    f16*   p123 = (f16*)(ws + P123_OFF);
    float* out  = (float*)d_out;

    const size_t need4 = P123_OFF + 3 * PART_SZ + ML_SZ + ADJ_SZ;
    int nib; size_t ml_off;
    if (ws_size >= need4) { nib = 4; ml_off = P123_OFF + 3 * PART_SZ; }
    else                  { nib = 2; ml_off = P123_OFF + 1 * PART_SZ; }
    float2* mlb  = (float2*)(ws + ml_off);
    u64*    adjb = (u64*)(ws + ml_off + ML_SZ);

    (void)hipFuncSetAttribute((const void*)attn_v4,
                              hipFuncAttributeMaxDynamicSharedMemorySize, LDSB_V4);

    cvt_fp16<<<4864, 256, 0, stream>>>(ns, Wq, Wk, Wv, Xh, Wqh, Wkh, Wvh);
    qkv_mfma<<<dim3(4, 64, 3), 256, 0, stream>>>(Xh, Wqh, Wkh, Wvh, qh, kh, vt);
    pack_adj<<<4096, 256, 0, stream>>>(adj, adjb);
    attn_v4<<<128 * nib, 256, LDSB_V4, stream>>>(qh, kh, vt, adjb, p0, p123, mlb);
    merge_p<<<4096, 256, 0, stream>>>(out, p0, p123, mlb, nib);
}